// Round 3
// baseline (285.564 us; speedup 1.0000x reference)
//
#include <hip/hip_runtime.h>
#include <math.h>

#define NN    128
#define NN2   16384        // N*N
#define CDIM  256
#define BV    8
#define MM    64
#define RR    128          // M*K pos rows
#define PP    8256         // N*(N+1)/2
#define NBLK  1032         // 66048 / 64 cols per block
#define BPB   129          // blocks per video (8256/64)
#define TEMP  0.1f
#define NEGIOU 0.5f

typedef __attribute__((ext_vector_type(8))) short bf16x8;
typedef __attribute__((ext_vector_type(4))) float f32x4;

static __device__ __forceinline__ unsigned short f2bf(float x) {
    union { float f; unsigned u; } c; c.f = x;
    unsigned r = c.u + 0x7FFFu + ((c.u >> 16) & 1u);   // RNE
    return (unsigned short)(r >> 16);
}

// ---------------- Kernel 1: fused top-2 + pos rows (fp32 + bf16 frag layout) -----
// One block per moment m: exact top-2 over masked iou2ds[m], then build pos rows
// 2m (top1) and 2m+1 (top2). posFrag layout (validated R2):
//   idx = (((c>>5)*8 + (r>>4))*64 + ((r&15) | (((c>>3)&3)<<4)))*8 + (c&7)
__global__ __launch_bounds__(256) void prep_kernel(const float* __restrict__ vfeat,
                                                   const float* __restrict__ iou2ds,
                                                   float* __restrict__ pos,
                                                   unsigned short* __restrict__ posFrag,
                                                   int* __restrict__ done) {
    int m = blockIdx.x, tid = threadIdx.x;
    if (m == 0 && tid == 0) *done = 0;         // counter for finish_kernel (stream-ordered)

    const float* src = iou2ds + (size_t)m * NN2;
    float v1 = -1e30f, v2 = -1e30f;
    int k1 = 0x7fffffff, k2 = 0x7fffffff;
    for (int k = tid; k < NN2; k += 256) {
        int i = k >> 7, j = k & 127;
        if (j < i) continue;                   // upper-triangular mask
        float v = src[k];
        if (v > v1 || (v == v1 && k < k1)) { v2 = v1; k2 = k1; v1 = v; k1 = k; }
        else if (v > v2 || (v == v2 && k < k2)) { v2 = v; k2 = k; }
    }
    __shared__ float sv[512];  __shared__ int sk[512];
    __shared__ float sv2[128]; __shared__ int sk2[128];
    __shared__ int sTop[2];
    sv[tid * 2] = v1; sv[tid * 2 + 1] = v2;
    sk[tid * 2] = k1; sk[tid * 2 + 1] = k2;
    __syncthreads();
    if (tid < 64) {
        float b1 = -1e30f, b2 = -1e30f; int c1 = 0x7fffffff, c2 = 0x7fffffff;
        for (int t = tid * 8; t < tid * 8 + 8; ++t) {
            float v = sv[t]; int k = sk[t];
            if (v > b1 || (v == b1 && k < c1)) { b2 = b1; c2 = c1; b1 = v; c1 = k; }
            else if (v > b2 || (v == b2 && k < c2)) { b2 = v; c2 = k; }
        }
        sv2[tid * 2] = b1; sv2[tid * 2 + 1] = b2;
        sk2[tid * 2] = c1; sk2[tid * 2 + 1] = c2;
    }
    __syncthreads();
    if (tid == 0) {
        float b1 = -1e30f, b2 = -1e30f; int c1 = 0x7fffffff, c2 = 0x7fffffff;
        for (int t = 0; t < 128; ++t) {
            float v = sv2[t]; int k = sk2[t];
            if (v > b1 || (v == b1 && k < c1)) { b2 = b1; c2 = c1; b1 = v; c1 = k; }
            else if (v > b2 || (v == b2 && k < c2)) { b2 = v; c2 = k; }
        }
        sTop[0] = c1; sTop[1] = c2;
    }
    __syncthreads();

    // rows: tids [0,128) -> row 2m (top1), [128,256) -> row 2m+1 (top2)
    int rloc = tid >> 7;
    int cloc = tid & 127;
    int r = m * 2 + rloc;
    int b = m >> 3;
    int ij = sTop[rloc];
    const float* base = vfeat + (size_t)b * CDIM * NN2 + ij;
    float va = base[(size_t)cloc * NN2];
    float vb = base[(size_t)(cloc + 128) * NN2];
    float ss = va * va + vb * vb;
#pragma unroll
    for (int o = 32; o > 0; o >>= 1) ss += __shfl_xor(ss, o, 64);
    __shared__ float sW[4];
    if ((tid & 63) == 0) sW[tid >> 6] = ss;
    __syncthreads();
    float inv = 1.0f / fmaxf(sqrtf(sW[rloc * 2] + sW[rloc * 2 + 1]), 1e-12f);
    float x0 = va * inv, x1 = vb * inv;
    pos[r * CDIM + cloc] = x0;
    pos[r * CDIM + cloc + 128] = x1;
    int c0 = cloc, c1c = cloc + 128;
    int i0 = (((c0 >> 5) * 8 + (r >> 4)) * 64 + ((r & 15) | (((c0 >> 3) & 3) << 4))) * 8 + (c0 & 7);
    int i1 = (((c1c >> 5) * 8 + (r >> 4)) * 64 + ((r & 15) | (((c1c >> 3) & 3) << 4))) * 8 + (c1c & 7);
    posFrag[i0] = f2bf(x0);
    posFrag[i1] = f2bf(x1);
}

// ---------------- Kernel 2: MFMA tall-skinny GEMM + norm + exp + masked row-sum --
// (unchanged from R2 — validated) 512 thr, 128 rows x 64 cols, K=256 in 4 phases,
// double-buffered LDS, A-frags in registers, one barrier per phase.
__global__ __launch_bounds__(512, 4) void neg_kernel(const float* __restrict__ vfeat,
                                                     const float* __restrict__ iou2d,
                                                     const unsigned short* __restrict__ posFrag,
                                                     float* __restrict__ part) {
    __shared__ unsigned short sB[2][2][4][64][8];   // [buf][s][ntile][slot][j]  16 KB
    __shared__ int   sIJ[64];
    __shared__ int   sMask[64];
    __shared__ float sNP[8][64];
    __shared__ float sInv[64];
    __shared__ float sNeg[RR];

    int tid = threadIdx.x;
    int bid = blockIdx.x;
    int b   = bid / BPB;
    int p0  = (bid - b * BPB) * 64;

    if (tid < RR) sNeg[tid] = 0.0f;
    if (tid < 64) {
        int p = p0 + tid;
        int i = (int)((257.0f - sqrtf(66049.0f - 8.0f * (float)p)) * 0.5f);
        if (i < 0) i = 0;
        while ((i + 1) * (257 - (i + 1)) / 2 <= p) ++i;
        while (i * (257 - i) / 2 > p) --i;
        int j = p - i * (257 - i) / 2 + i;
        int ij = i * NN + j;
        sIJ[tid] = ij;
        int mask = 0;
#pragma unroll
        for (int t = 0; t < 4; ++t) {
            float iv = iou2d[((size_t)(4 * b + t)) * NN2 + ij];
            mask |= (iv > NEGIOU) ? (1 << t) : 0;
        }
        sMask[tid] = mask;
    }

    int lane = tid & 63;
    int col  = tid & 63;
    int wv   = tid >> 6;                    // 0..7
    int rowgroup = wv >> 1;                 // 0..3 -> rows rowgroup*32
    int colgroup = wv & 1;                  // 0..1 -> cols colgroup*32

    bf16x8 afrag[2][8];
    const bf16x8* pf = (const bf16x8*)posFrag;
#pragma unroll
    for (int mt = 0; mt < 2; ++mt)
#pragma unroll
        for (int s = 0; s < 8; ++s)
            afrag[mt][s] = pf[(s * 8 + rowgroup * 2 + mt) * 64 + lane];

    __syncthreads();                        // sIJ/sMask ready

    const float* vcol = vfeat + (size_t)b * CDIM * NN2 + sIJ[col];

    f32x4 acc[2][2];
#pragma unroll
    for (int mt = 0; mt < 2; ++mt)
#pragma unroll
        for (int nt = 0; nt < 2; ++nt)
#pragma unroll
            for (int e = 0; e < 4; ++e) acc[mt][nt][e] = 0.0f;

    float nrm = 0.0f;
    float r[8];
#pragma unroll
    for (int j = 0; j < 8; ++j) r[j] = vcol[(size_t)(wv * 8 + j) * NN2];

    int s_loc = wv >> 2;
    int slot  = (col & 15) | ((wv & 3) << 4);
    int nt_w  = col >> 4;

    for (int ph = 0; ph < 4; ++ph) {
        union { bf16x8 v; unsigned u[4]; } pkd;
#pragma unroll
        for (int j = 0; j < 4; ++j)
            pkd.u[j] = (unsigned)f2bf(r[2 * j]) | ((unsigned)f2bf(r[2 * j + 1]) << 16);
#pragma unroll
        for (int j = 0; j < 8; ++j) nrm = fmaf(r[j], r[j], nrm);
        *(bf16x8*)&sB[ph & 1][s_loc][nt_w][slot][0] = pkd.v;
        __syncthreads();
        if (ph < 3) {
#pragma unroll
            for (int j = 0; j < 8; ++j)
                r[j] = vcol[(size_t)((ph + 1) * 64 + wv * 8 + j) * NN2];
        }
#pragma unroll
        for (int s = 0; s < 2; ++s)
#pragma unroll
            for (int ntl = 0; ntl < 2; ++ntl) {
                bf16x8 bfrag = *(const bf16x8*)&sB[ph & 1][s][colgroup * 2 + ntl][lane][0];
#pragma unroll
                for (int mt = 0; mt < 2; ++mt)
                    acc[mt][ntl] = __builtin_amdgcn_mfma_f32_16x16x32_bf16(
                        afrag[mt][ph * 2 + s], bfrag, acc[mt][ntl], 0, 0, 0);
            }
    }

    sNP[wv][col] = nrm;
    __syncthreads();
    if (tid < 64) {
        float s = 0.0f;
        for (int t = 0; t < 8; ++t) s += sNP[t][tid];
        sInv[tid] = 10.0f / fmaxf(sqrtf(s), 1e-12f);   // 1/(T*norm), T=0.1
    }
    __syncthreads();

#pragma unroll
    for (int mt = 0; mt < 2; ++mt)
#pragma unroll
        for (int ntl = 0; ntl < 2; ++ntl)
#pragma unroll
            for (int reg = 0; reg < 4; ++reg) {
                int row = rowgroup * 32 + mt * 16 + ((lane >> 4) << 2) + reg;
                int cl  = colgroup * 32 + ntl * 16 + (lane & 15);
                float e = __expf(acc[mt][ntl][reg] * sInv[cl]);
                int excl = ((row >> 4) == b) & ((sMask[cl] >> ((row >> 2) & 3)) & 1);
                e = excl ? 0.0f : e;
#pragma unroll
                for (int off = 1; off < 16; off <<= 1) e += __shfl_xor(e, off, 64);
                if ((lane & 15) == 0) atomicAdd(&sNeg[row], e);
            }
    __syncthreads();
    if (tid < RR) part[(size_t)tid * NBLK + bid] = sNeg[tid];
}

// ---------------- Kernel 3: row-reduce + last-block loss -------------------------
__global__ __launch_bounds__(256) void finish_kernel(const float* __restrict__ part,
                                                     const float* __restrict__ pos,
                                                     float* __restrict__ neg,
                                                     int* __restrict__ done,
                                                     float* __restrict__ out) {
    int r = blockIdx.x, tid = threadIdx.x;
    const float* row = part + (size_t)r * NBLK;
    float s = 0.0f;
    for (int t = tid; t < NBLK; t += 256) s += row[t];
#pragma unroll
    for (int o = 32; o > 0; o >>= 1) s += __shfl_xor(s, o, 64);
    __shared__ float sw[4];
    __shared__ int amLast;
    if ((tid & 63) == 0) sw[tid >> 6] = s;
    __syncthreads();
    if (tid == 0) {
        float v = sw[0] + sw[1] + sw[2] + sw[3];
        __hip_atomic_store(&neg[r], v, __ATOMIC_RELEASE, __HIP_MEMORY_SCOPE_AGENT);
        int prev = __hip_atomic_fetch_add(done, 1, __ATOMIC_ACQ_REL, __HIP_MEMORY_SCOPE_AGENT);
        amLast = (prev == RR - 1);
    }
    __syncthreads();
    if (!amLast) return;

    // last block: 512 pair dots + log-sum-exp + mean
    float local = 0.0f;
    for (int e = tid; e < 512; e += 256) {
        int si = e >> 4;
        int aa = (e >> 2) & 3;
        int bb = e & 3;
        int rr = si * 4 + aa;
        int pp = si * 4 + bb;
        const float4* pr = (const float4*)(pos + rr * CDIM);
        const float4* pq = (const float4*)(pos + pp * CDIM);
        float dot = 0.0f;
        for (int c = 0; c < CDIM / 4; ++c) {
            float4 a = pr[c], bv = pq[c];
            dot += a.x * bv.x + a.y * bv.y + a.z * bv.z + a.w * bv.w;
        }
        float x = dot / TEMP;                  // MARGIN = 0
        float ns = __hip_atomic_load(&neg[rr], __ATOMIC_ACQUIRE, __HIP_MEMORY_SCOPE_AGENT);
        local += logf(__expf(x) + ns) - x;
    }
#pragma unroll
    for (int o = 32; o > 0; o >>= 1) local += __shfl_xor(local, o, 64);
    __shared__ float sred[4];
    if ((tid & 63) == 0) sred[tid >> 6] = local;
    __syncthreads();
    if (tid == 0) out[0] = (sred[0] + sred[1] + sred[2] + sred[3]) / 512.0f;
}

extern "C" void kernel_launch(void* const* d_in, const int* in_sizes, int n_in,
                              void* d_out, int out_size, void* d_ws, size_t ws_size,
                              hipStream_t stream) {
    (void)in_sizes; (void)n_in; (void)out_size; (void)ws_size;
    const float* vfeat  = (const float*)d_in[0];
    const float* iou2d  = (const float*)d_in[4];
    const float* iou2ds = (const float*)d_in[5];

    float* ws = (float*)d_ws;
    float*          pos     = ws;                                   // 32768 f
    unsigned short* posFrag = (unsigned short*)(ws + 32768);        // 16384 f-equiv
    float*          part    = ws + 32768 + 16384;                   // 128*1032 f
    float*          neg     = part + RR * NBLK;                     // 128 f
    int*            done    = (int*)(neg + RR);                     // 1 int

    prep_kernel  <<<MM, 256, 0, stream>>>(vfeat, iou2ds, pos, posFrag, done);
    neg_kernel   <<<NBLK, 512, 0, stream>>>(vfeat, iou2d, posFrag, part);
    finish_kernel<<<RR, 256, 0, stream>>>(part, pos, neg, done, (float*)d_out);
}

// Round 4
// 256.893 us; speedup vs baseline: 1.1116x; 1.1116x over previous
//
#include <hip/hip_runtime.h>
#include <math.h>

#define NN    128
#define NN2   16384        // N*N
#define CDIM  256
#define BV    8
#define MM    64
#define RR    128          // M*K pos rows
#define PP    8256         // N*(N+1)/2
#define NBLK  1032         // 66048 / 64 cols per block
#define BPB   129          // blocks per video (8256/64)
#define TEMP  0.1f
#define NEGIOU 0.5f

typedef __attribute__((ext_vector_type(8))) short bf16x8;
typedef __attribute__((ext_vector_type(4))) float f32x4;

static __device__ __forceinline__ unsigned short f2bf(float x) {
    union { float f; unsigned u; } c; c.f = x;
    unsigned r = c.u + 0x7FFFu + ((c.u >> 16) & 1u);   // RNE
    return (unsigned short)(r >> 16);
}

// ---------------- Kernel 1a: partial top-2 per (moment, quarter) -----------------
__global__ __launch_bounds__(256) void topk_part_kernel(const float* __restrict__ iou2ds,
                                                        float* __restrict__ pv,
                                                        int* __restrict__ pk) {
    int m = blockIdx.x, q = blockIdx.y, tid = threadIdx.x;
    const float* src = iou2ds + (size_t)m * NN2;
    float v1 = -1e30f, v2 = -1e30f;
    int k1 = 0x7fffffff, k2 = 0x7fffffff;
    int base = q * 4096;
#pragma unroll
    for (int i = 0; i < 16; ++i) {
        int k = base + tid + 256 * i;
        int r = k >> 7, c = k & 127;
        if (c < r) continue;                     // upper-triangular mask
        float v = src[k];
        if (v > v1 || (v == v1 && k < k1)) { v2 = v1; k2 = k1; v1 = v; k1 = k; }
        else if (v > v2 || (v == v2 && k < k2)) { v2 = v; k2 = k; }
    }
    __shared__ float sv[512];  __shared__ int sk[512];
    __shared__ float sv2[128]; __shared__ int sk2[128];
    sv[tid * 2] = v1; sv[tid * 2 + 1] = v2;
    sk[tid * 2] = k1; sk[tid * 2 + 1] = k2;
    __syncthreads();
    if (tid < 64) {
        float b1 = -1e30f, b2 = -1e30f; int c1 = 0x7fffffff, c2 = 0x7fffffff;
        for (int t = tid * 8; t < tid * 8 + 8; ++t) {
            float v = sv[t]; int k = sk[t];
            if (v > b1 || (v == b1 && k < c1)) { b2 = b1; c2 = c1; b1 = v; c1 = k; }
            else if (v > b2 || (v == b2 && k < c2)) { b2 = v; c2 = k; }
        }
        sv2[tid * 2] = b1; sv2[tid * 2 + 1] = b2;
        sk2[tid * 2] = c1; sk2[tid * 2 + 1] = c2;
    }
    __syncthreads();
    if (tid == 0) {
        float b1 = -1e30f, b2 = -1e30f; int c1 = 0x7fffffff, c2 = 0x7fffffff;
        for (int t = 0; t < 128; ++t) {
            float v = sv2[t]; int k = sk2[t];
            if (v > b1 || (v == b1 && k < c1)) { b2 = b1; c2 = c1; b1 = v; c1 = k; }
            else if (v > b2 || (v == b2 && k < c2)) { b2 = v; c2 = k; }
        }
        pv[(m * 4 + q) * 2] = b1; pv[(m * 4 + q) * 2 + 1] = b2;
        pk[(m * 4 + q) * 2] = c1; pk[(m * 4 + q) * 2 + 1] = c2;
    }
}

// ---------------- Kernel 2: merge partials, pos fp32 + pos bf16 frag layout ------
// posFrag layout: [s=k>>5][mt=r>>4][slot=(r&15)|(((k>>3)&3)<<4)][j=k&7]  (ushort)
__global__ __launch_bounds__(64) void posfeat_kernel(const float* __restrict__ vfeat,
                                                     const float* __restrict__ pv,
                                                     const int* __restrict__ pk,
                                                     float* __restrict__ pos,
                                                     unsigned short* __restrict__ posFrag) {
    int r = blockIdx.x, lane = threadIdx.x;
    int m = r >> 1, b = m >> 3, kk = r & 1;
    float b1 = -1e30f, b2 = -1e30f; int c1 = 0x7fffffff, c2 = 0x7fffffff;
    for (int t = 0; t < 8; ++t) {
        float v = pv[m * 8 + t]; int k = pk[m * 8 + t];
        if (v > b1 || (v == b1 && k < c1)) { b2 = b1; c2 = c1; b1 = v; c1 = k; }
        else if (v > b2 || (v == b2 && k < c2)) { b2 = v; c2 = k; }
    }
    int ij = kk ? c2 : c1;
    const float* base = vfeat + (size_t)b * CDIM * NN2 + ij;
    float v[4];
    float ss = 0.0f;
#pragma unroll
    for (int q = 0; q < 4; ++q) {
        int c = lane + 64 * q;
        v[q] = base[(size_t)c * NN2];
        ss += v[q] * v[q];
    }
#pragma unroll
    for (int o = 32; o > 0; o >>= 1) ss += __shfl_xor(ss, o, 64);
    float inv = 1.0f / fmaxf(sqrtf(ss), 1e-12f);
#pragma unroll
    for (int q = 0; q < 4; ++q) {
        int c = lane + 64 * q;
        float val = v[q] * inv;
        pos[r * CDIM + c] = val;
        int idx = (((c >> 5) * 8 + (r >> 4)) * 64 + ((r & 15) | (((c >> 3) & 3) << 4))) * 8 + (c & 7);
        posFrag[idx] = f2bf(val);
    }
}

// ---------------- Kernel 3: MFMA tall-skinny GEMM + norm + exp + masked row-sum --
// Block: 512 thr (8 waves), 128 rows x 64 cols, K=256 in 4 phases of BK=64,
// double-buffered LDS, A-frags in registers, one barrier per phase.
__global__ __launch_bounds__(512, 4) void neg_kernel(const float* __restrict__ vfeat,
                                                     const float* __restrict__ iou2d,
                                                     const unsigned short* __restrict__ posFrag,
                                                     float* __restrict__ part) {
    __shared__ unsigned short sB[2][2][4][64][8];   // [buf][s][ntile][slot][j]  16 KB
    __shared__ int   sIJ[64];
    __shared__ int   sMask[64];
    __shared__ float sNP[8][64];
    __shared__ float sInv[64];
    __shared__ float sNeg[RR];

    int tid = threadIdx.x;
    int bid = blockIdx.x;
    int b   = bid / BPB;
    int p0  = (bid - b * BPB) * 64;

    if (tid < RR) sNeg[tid] = 0.0f;
    if (tid < 64) {
        int p = p0 + tid;
        int i = (int)((257.0f - sqrtf(66049.0f - 8.0f * (float)p)) * 0.5f);
        if (i < 0) i = 0;
        while ((i + 1) * (257 - (i + 1)) / 2 <= p) ++i;
        while (i * (257 - i) / 2 > p) --i;
        int j = p - i * (257 - i) / 2 + i;
        int ij = i * NN + j;
        sIJ[tid] = ij;
        int mask = 0;
#pragma unroll
        for (int t = 0; t < 4; ++t) {
            float iv = iou2d[((size_t)(4 * b + t)) * NN2 + ij];
            mask |= (iv > NEGIOU) ? (1 << t) : 0;
        }
        sMask[tid] = mask;
    }

    int lane = tid & 63;
    int col  = tid & 63;
    int wv   = tid >> 6;                    // 0..7
    int rowgroup = wv >> 1;                 // 0..3 -> rows rowgroup*32
    int colgroup = wv & 1;                  // 0..1 -> cols colgroup*32

    bf16x8 afrag[2][8];
    const bf16x8* pf = (const bf16x8*)posFrag;
#pragma unroll
    for (int mt = 0; mt < 2; ++mt)
#pragma unroll
        for (int s = 0; s < 8; ++s)
            afrag[mt][s] = pf[(s * 8 + rowgroup * 2 + mt) * 64 + lane];

    __syncthreads();                        // sIJ/sMask ready

    const float* vcol = vfeat + (size_t)b * CDIM * NN2 + sIJ[col];

    f32x4 acc[2][2];
#pragma unroll
    for (int mt = 0; mt < 2; ++mt)
#pragma unroll
        for (int nt = 0; nt < 2; ++nt)
#pragma unroll
            for (int e = 0; e < 4; ++e) acc[mt][nt][e] = 0.0f;

    float nrm = 0.0f;
    float r[8];
#pragma unroll
    for (int j = 0; j < 8; ++j) r[j] = vcol[(size_t)(wv * 8 + j) * NN2];

    int s_loc = wv >> 2;
    int slot  = (col & 15) | ((wv & 3) << 4);
    int nt_w  = col >> 4;

    for (int ph = 0; ph < 4; ++ph) {
        union { bf16x8 v; unsigned u[4]; } pkd;
#pragma unroll
        for (int j = 0; j < 4; ++j)
            pkd.u[j] = (unsigned)f2bf(r[2 * j]) | ((unsigned)f2bf(r[2 * j + 1]) << 16);
#pragma unroll
        for (int j = 0; j < 8; ++j) nrm = fmaf(r[j], r[j], nrm);
        *(bf16x8*)&sB[ph & 1][s_loc][nt_w][slot][0] = pkd.v;
        __syncthreads();
        if (ph < 3) {
#pragma unroll
            for (int j = 0; j < 8; ++j)
                r[j] = vcol[(size_t)((ph + 1) * 64 + wv * 8 + j) * NN2];
        }
#pragma unroll
        for (int s = 0; s < 2; ++s)
#pragma unroll
            for (int ntl = 0; ntl < 2; ++ntl) {
                bf16x8 bfrag = *(const bf16x8*)&sB[ph & 1][s][colgroup * 2 + ntl][lane][0];
#pragma unroll
                for (int mt = 0; mt < 2; ++mt)
                    acc[mt][ntl] = __builtin_amdgcn_mfma_f32_16x16x32_bf16(
                        afrag[mt][ph * 2 + s], bfrag, acc[mt][ntl], 0, 0, 0);
            }
    }

    sNP[wv][col] = nrm;
    __syncthreads();
    if (tid < 64) {
        float s = 0.0f;
        for (int t = 0; t < 8; ++t) s += sNP[t][tid];
        sInv[tid] = 10.0f / fmaxf(sqrtf(s), 1e-12f);   // 1/(T*norm), T=0.1
    }
    __syncthreads();

#pragma unroll
    for (int mt = 0; mt < 2; ++mt)
#pragma unroll
        for (int ntl = 0; ntl < 2; ++ntl)
#pragma unroll
            for (int reg = 0; reg < 4; ++reg) {
                int row = rowgroup * 32 + mt * 16 + ((lane >> 4) << 2) + reg;
                int cl  = colgroup * 32 + ntl * 16 + (lane & 15);
                float e = __expf(acc[mt][ntl][reg] * sInv[cl]);
                int excl = ((row >> 4) == b) & ((sMask[cl] >> ((row >> 2) & 3)) & 1);
                e = excl ? 0.0f : e;
#pragma unroll
                for (int off = 1; off < 16; off <<= 1) e += __shfl_xor(e, off, 64);
                if ((lane & 15) == 0) atomicAdd(&sNeg[row], e);
            }
    __syncthreads();
    if (tid < RR) part[(size_t)tid * NBLK + bid] = sNeg[tid];
}

// ---------------- Kernel 4: reduce per-block partials -> neg_sum[128] ------------
__global__ __launch_bounds__(256) void reduce_kernel(const float* __restrict__ part,
                                                     float* __restrict__ neg) {
    int r = blockIdx.x, tid = threadIdx.x;
    const float* row = part + (size_t)r * NBLK;
    float s = 0.0f;
    for (int t = tid; t < NBLK; t += 256) s += row[t];
#pragma unroll
    for (int o = 32; o > 0; o >>= 1) s += __shfl_xor(s, o, 64);
    __shared__ float sw[4];
    if ((tid & 63) == 0) sw[tid >> 6] = s;
    __syncthreads();
    if (tid == 0) neg[r] = sw[0] + sw[1] + sw[2] + sw[3];
}

// ---------------- Kernel 5: 512 pair dots + log-sum-exp + mean -------------------
__global__ __launch_bounds__(256) void loss_kernel(const float* __restrict__ pos,
                                                   const float* __restrict__ neg,
                                                   float* __restrict__ out) {
    int tid = threadIdx.x;
    float local = 0.0f;
    for (int e = tid; e < 512; e += 256) {
        int s  = e >> 4;
        int aa = (e >> 2) & 3;
        int bb = e & 3;
        int rr = s * 4 + aa;
        int pp = s * 4 + bb;
        const float4* pr = (const float4*)(pos + rr * CDIM);
        const float4* pq = (const float4*)(pos + pp * CDIM);
        float dot = 0.0f;
        for (int c = 0; c < CDIM / 4; ++c) {
            float4 a = pr[c], bv = pq[c];
            dot += a.x * bv.x + a.y * bv.y + a.z * bv.z + a.w * bv.w;
        }
        float x = dot / TEMP;                  // MARGIN = 0
        local += logf(__expf(x) + neg[rr]) - x;
    }
#pragma unroll
    for (int o = 32; o > 0; o >>= 1) local += __shfl_xor(local, o, 64);
    __shared__ float sred[4];
    if ((tid & 63) == 0) sred[tid >> 6] = local;
    __syncthreads();
    if (tid == 0) out[0] = (sred[0] + sred[1] + sred[2] + sred[3]) / 512.0f;
}

extern "C" void kernel_launch(void* const* d_in, const int* in_sizes, int n_in,
                              void* d_out, int out_size, void* d_ws, size_t ws_size,
                              hipStream_t stream) {
    (void)in_sizes; (void)n_in; (void)out_size; (void)ws_size;
    const float* vfeat  = (const float*)d_in[0];
    const float* iou2d  = (const float*)d_in[4];
    const float* iou2ds = (const float*)d_in[5];

    float* ws = (float*)d_ws;
    float*          pos     = ws;                                   // 32768 f
    unsigned short* posFrag = (unsigned short*)(ws + 32768);        // 16384 f-equiv
    float*          pv      = ws + 32768 + 16384;                   // 512 f
    int*            pk      = (int*)(pv + 512);                     // 512 i
    float*          part    = pv + 1024;                            // 128*1032 f
    float*          neg     = part + RR * NBLK;                     // 128 f

    topk_part_kernel<<<dim3(MM, 4), 256, 0, stream>>>(iou2ds, pv, pk);
    posfeat_kernel  <<<RR, 64, 0, stream>>>(vfeat, pv, pk, pos, posFrag);
    neg_kernel      <<<NBLK, 512, 0, stream>>>(vfeat, iou2d, posFrag, part);
    reduce_kernel   <<<RR, 256, 0, stream>>>(part, neg);
    loss_kernel     <<<1, 256, 0, stream>>>(pos, neg, (float*)d_out);
}